// Round 1
// baseline (140.702 us; speedup 1.0000x reference)
//
#include <hip/hip_runtime.h>
#include <math.h>

#define NN_ 50000
#define DD_ 256
#define HH_ 512
#define OO_ 64
#define PP_ 1024

// ---------------- K1: c[i] = sum_o W2[o][i]^2 ----------------
__global__ void k_c(const float* __restrict__ W2, float* __restrict__ c) {
    int i = blockIdx.x * 256 + threadIdx.x;
    if (i < HH_) {
        float s = 0.f;
        #pragma unroll
        for (int o = 0; o < OO_; ++o) { float w = W2[o * HH_ + i]; s += w * w; }
        c[i] = s;
    }
}

// ---------------- K2: h[r][j] = tanh( x[idx[r]] . W1[j] + b1[j] ), r in [0,4096) ----------------
// rows 0..1023: ap, 1024..2047: p, 2048..3071: an, 3072..4095: n
__global__ __launch_bounds__(256) void k_gemm1(
    const float* __restrict__ x, const float* __restrict__ W1, const float* __restrict__ b1,
    const int* __restrict__ i0, const int* __restrict__ i1,
    const int* __restrict__ i2, const int* __restrict__ i3,
    float* __restrict__ h) {
    __shared__ float As[16][65];
    __shared__ float Bs[16][65];
    __shared__ int sidx[64];
    const int t = threadIdx.x;
    const int bx = blockIdx.x;   // col block 0..7
    const int by = blockIdx.y;   // row block 0..63
    const int rbase = by * 64;
    const int set = rbase >> 10;
    const int* I = (set == 0) ? i0 : (set == 1) ? i1 : (set == 2) ? i2 : i3;
    if (t < 64) sidx[t] = I[(rbase & 1023) + t];
    __syncthreads();
    const int tx = t & 15, ty = t >> 4;
    const int lkk = t & 15;   // k-in-tile for loads
    const int lr  = t >> 4;   // 0..15
    float acc[4][4] = {};
    for (int k0 = 0; k0 < DD_; k0 += 16) {
        #pragma unroll
        for (int rr = 0; rr < 64; rr += 16) {
            int r = lr + rr;
            As[lkk][r] = x[(size_t)sidx[r] * DD_ + k0 + lkk];
        }
        #pragma unroll
        for (int jj = 0; jj < 64; jj += 16) {
            int j = lr + jj;
            Bs[lkk][j] = W1[(size_t)(bx * 64 + j) * DD_ + k0 + lkk];
        }
        __syncthreads();
        #pragma unroll
        for (int kk = 0; kk < 16; ++kk) {
            float a[4], b[4];
            #pragma unroll
            for (int u = 0; u < 4; ++u) a[u] = As[kk][ty * 4 + u];
            #pragma unroll
            for (int v = 0; v < 4; ++v) b[v] = Bs[kk][tx * 4 + v];
            #pragma unroll
            for (int u = 0; u < 4; ++u)
                #pragma unroll
                for (int v = 0; v < 4; ++v)
                    acc[u][v] += a[u] * b[v];
        }
        __syncthreads();
    }
    const int j0 = bx * 64 + tx * 4;
    #pragma unroll
    for (int u = 0; u < 4; ++u) {
        int r = rbase + ty * 4 + u;
        float4 hv;
        hv.x = tanhf(acc[u][0] + b1[j0 + 0]);
        hv.y = tanhf(acc[u][1] + b1[j0 + 1]);
        hv.z = tanhf(acc[u][2] + b1[j0 + 2]);
        hv.w = tanhf(acc[u][3] + b1[j0 + 3]);
        *reinterpret_cast<float4*>(&h[(size_t)r * HH_ + j0]) = hv;
    }
}

// ---------------- K3a: M rows (3 terms x 2048 pairs) x H, sign folded in ----------------
__global__ void k_M(const float* __restrict__ h, const float* __restrict__ c,
                    float* __restrict__ M) {
    int gid = blockIdx.x * 256 + threadIdx.x;  // 0..2048*512-1
    int i = gid & (HH_ - 1);
    int sp = gid >> 9;        // 0..2047
    int s = sp >> 10;         // 0=pos, 1=neg
    int p = sp & 1023;
    float ha = h[((size_t)(s * 2) * 1024 + p) * HH_ + i];
    float hb = h[((size_t)(s * 2 + 1) * 1024 + p) * HH_ + i];
    float ci = c[i];
    float da = 1.f - ha * ha, db = 1.f - hb * hb;
    float sign = s ? -1.f : 1.f;
    float S11 = da * da * ci;
    float S12 = da * db * ci;
    float S22 = db * db * ci;
    const size_t TERM = (size_t)2048 * HH_;
    M[0 * TERM + gid] = sign * S11;
    M[1 * TERM + gid] = sign * (-2.f * S12);
    M[2 * TERM + gid] = sign * S22;
}

// ---------------- K3b: X rows (3 terms x 2048 pairs) x D ----------------
__global__ void k_X(const float* __restrict__ x,
                    const int* __restrict__ i0, const int* __restrict__ i1,
                    const int* __restrict__ i2, const int* __restrict__ i3,
                    float* __restrict__ X) {
    int gid = blockIdx.x * 256 + threadIdx.x;  // 0..2048*256-1
    int j = gid & (DD_ - 1);
    int sp = gid >> 8;
    int s = sp >> 10, p = sp & 1023;
    int ia = s ? i2[p] : i0[p];
    int ib = s ? i3[p] : i1[p];
    float xa = x[(size_t)ia * DD_ + j];
    float xb = x[(size_t)ib * DD_ + j];
    const size_t TERM = (size_t)2048 * DD_;
    X[0 * TERM + gid] = xa * xa;
    X[1 * TERM + gid] = xa * xb;
    X[2 * TERM + gid] = xb * xb;
}

// ---------------- K4: partial[kb][i][j] = sum_{k in chunk} M[k][i] * X[k][j] ----------------
__global__ __launch_bounds__(256) void k_gemm2(
    const float* __restrict__ M, const float* __restrict__ X,
    float* __restrict__ part) {
    __shared__ float Ms[16][65];
    __shared__ float Xs[16][65];
    const int t = threadIdx.x;
    const int bx = blockIdx.x;   // j block 0..3
    const int by = blockIdx.y;   // i block 0..7
    const int kb = blockIdx.z;   // 0..7 split-K
    const int tx = t & 15, ty = t >> 4;
    const int li = t & 63;  // 0..63
    const int lk = t >> 6;  // 0..3
    float acc[4][4] = {};
    const int kend = kb * 768 + 768;
    for (int k0 = kb * 768; k0 < kend; k0 += 16) {
        #pragma unroll
        for (int kk4 = 0; kk4 < 16; kk4 += 4) {
            int kk = lk + kk4;
            Ms[kk][li] = M[(size_t)(k0 + kk) * HH_ + by * 64 + li];
            Xs[kk][li] = X[(size_t)(k0 + kk) * DD_ + bx * 64 + li];
        }
        __syncthreads();
        #pragma unroll
        for (int kk = 0; kk < 16; ++kk) {
            float a[4], b[4];
            #pragma unroll
            for (int u = 0; u < 4; ++u) a[u] = Ms[kk][ty * 4 + u];
            #pragma unroll
            for (int v = 0; v < 4; ++v) b[v] = Xs[kk][tx * 4 + v];
            #pragma unroll
            for (int u = 0; u < 4; ++u)
                #pragma unroll
                for (int v = 0; v < 4; ++v)
                    acc[u][v] += a[u] * b[v];
        }
        __syncthreads();
    }
    const int j0 = bx * 64 + tx * 4;
    #pragma unroll
    for (int u = 0; u < 4; ++u) {
        int i = by * 64 + ty * 4 + u;
        float4 v4 = {acc[u][0], acc[u][1], acc[u][2], acc[u][3]};
        *reinterpret_cast<float4*>(&part[((size_t)kb * HH_ + i) * DD_ + j0]) = v4;
    }
}

// ---------------- K4b: reduce split-K partials -> out[0 .. H*D) ----------------
__global__ void k_w1red(const float* __restrict__ part, float* __restrict__ out) {
    int gid = blockIdx.x * 256 + threadIdx.x;  // 0..131071
    float s = 0.f;
    #pragma unroll
    for (int kb = 0; kb < 8; ++kb) s += part[(size_t)kb * (HH_ * DD_) + gid];
    out[gid] = s;  // layout i*D + j already matches
}

// ---------------- K5a: partial column sums of M -> pb1[kb][i] ----------------
__global__ void k_b1part(const float* __restrict__ M, float* __restrict__ pb1) {
    int i = blockIdx.x * 256 + threadIdx.x;  // 0..511
    int kb = blockIdx.y;                      // 0..31 (chunks of 192)
    float s = 0.f;
    for (int k = kb * 192; k < kb * 192 + 192; ++k)
        s += M[(size_t)k * HH_ + i];
    pb1[kb * HH_ + i] = s;
}

// ---------------- K6a: partial hd sums -> phd[kb][i] ----------------
__global__ void k_hdpart(const float* __restrict__ h, float* __restrict__ phd) {
    int i = blockIdx.x * 256 + threadIdx.x;  // 0..511
    int kb = blockIdx.y;                      // 0..15 (p chunks of 64)
    float s = 0.f;
    for (int p = kb * 64; p < kb * 64 + 64; ++p) {
        float d0 = h[(size_t)p * HH_ + i] - h[(size_t)(1024 + p) * HH_ + i];
        float d1 = h[(size_t)(2048 + p) * HH_ + i] - h[(size_t)(3072 + p) * HH_ + i];
        s += d0 * d0 - d1 * d1;
    }
    phd[kb * HH_ + i] = s;
}

// ---------------- K6b: finalize b1d and hdsum ----------------
__global__ void k_small(const float* __restrict__ pb1, const float* __restrict__ phd,
                        float* __restrict__ out, float* __restrict__ hds) {
    int i = blockIdx.x * 256 + threadIdx.x;  // 0..511
    float sb = 0.f;
    #pragma unroll
    for (int kb = 0; kb < 32; ++kb) sb += pb1[kb * HH_ + i];
    out[HH_ * DD_ + i] = sb;
    float sh = 0.f;
    #pragma unroll
    for (int kb = 0; kb < 16; ++kb) sh += phd[kb * HH_ + i];
    hds[i] = sh;
}

// ---------------- K6c: W2d broadcast + b2d zeros ----------------
__global__ void k_w2(const float* __restrict__ hds, float* __restrict__ out) {
    int gid = blockIdx.x * 256 + threadIdx.x;  // 0..32831
    const int base = HH_ * DD_ + HH_;
    if (gid < OO_ * HH_) out[base + gid] = hds[gid & (HH_ - 1)];
    else if (gid < OO_ * HH_ + OO_) out[base + gid] = 0.f;
}

extern "C" void kernel_launch(void* const* d_in, const int* in_sizes, int n_in,
                              void* d_out, int out_size, void* d_ws, size_t ws_size,
                              hipStream_t stream) {
    const float* x  = (const float*)d_in[0];
    const float* W1 = (const float*)d_in[1];
    const float* b1 = (const float*)d_in[2];
    const float* W2 = (const float*)d_in[3];
    // d_in[4] = b2 (unused: b2 Jacobians cancel)
    const int* ap = (const int*)d_in[5];
    const int* p  = (const int*)d_in[6];
    const int* an = (const int*)d_in[7];
    const int* nI = (const int*)d_in[8];
    float* out = (float*)d_out;
    float* ws = (float*)d_ws;

    // workspace layout (floats)
    float* c    = ws;                       // 512 (pad to 1024)
    float* h    = ws + 1024;                // 4096*512 = 2097152
    float* M    = h + 2097152;              // 6144*512 = 3145728
    float* X    = M + 3145728;              // 6144*256 = 1572864
    float* part = X + 1572864;              // 8*131072 = 1048576
    float* pb1  = part + 1048576;           // 32*512
    float* phd  = pb1 + 16384;              // 16*512
    float* hds  = phd + 8192;               // 512
    // total ~30.1 MB

    k_c<<<dim3(2), dim3(256), 0, stream>>>(W2, c);
    k_gemm1<<<dim3(8, 64), dim3(256), 0, stream>>>(x, W1, b1, ap, p, an, nI, h);
    k_M<<<dim3(4096), dim3(256), 0, stream>>>(h, c, M);
    k_X<<<dim3(2048), dim3(256), 0, stream>>>(x, ap, p, an, nI, X);
    k_gemm2<<<dim3(4, 8, 8), dim3(256), 0, stream>>>(M, X, part);
    k_w1red<<<dim3(512), dim3(256), 0, stream>>>(part, out);
    k_b1part<<<dim3(2, 32), dim3(256), 0, stream>>>(M, pb1);
    k_hdpart<<<dim3(2, 16), dim3(256), 0, stream>>>(h, phd);
    k_small<<<dim3(2), dim3(256), 0, stream>>>(pb1, phd, out, hds);
    k_w2<<<dim3(129), dim3(256), 0, stream>>>(hds, out);
}

// Round 2
// 98.674 us; speedup vs baseline: 1.4259x; 1.4259x over previous
//
#include <hip/hip_runtime.h>
#include <math.h>

#define DD_ 256
#define HH_ 512
#define OO_ 64

// ---------------- K1: c[i] = sum_o W2[o][i]^2 ----------------
__global__ void k_c(const float* __restrict__ W2, float* __restrict__ c) {
    int i = blockIdx.x * 256 + threadIdx.x;
    if (i < HH_) {
        float s = 0.f;
        #pragma unroll
        for (int o = 0; o < OO_; ++o) { float w = W2[o * HH_ + i]; s += w * w; }
        c[i] = s;
    }
}

// ---------------- K2: h[r][j] = tanh( x[idx[r]] . W1[j] + b1[j] ) ----------------
// tile 64 rows x 32 cols; grid (16, 64) = 1024 blocks (4 blocks/CU)
__global__ __launch_bounds__(256) void k_gemm1(
    const float* __restrict__ x, const float* __restrict__ W1, const float* __restrict__ b1,
    const int* __restrict__ i0, const int* __restrict__ i1,
    const int* __restrict__ i2, const int* __restrict__ i3,
    float* __restrict__ h) {
    __shared__ float As[16][68];   // [k][row], pad 68 keeps 16B align, rotates banks by 4
    __shared__ float Bs[16][36];   // [k][col]
    __shared__ int sidx[64];
    const int t = threadIdx.x;
    const int bx = blockIdx.x;   // col block 0..15 (32 cols)
    const int by = blockIdx.y;   // row block 0..63 (64 rows)
    const int rbase = by * 64;
    const int set = rbase >> 10;
    const int* I = (set == 0) ? i0 : (set == 1) ? i1 : (set == 2) ? i2 : i3;
    if (t < 64) sidx[t] = I[(rbase & 1023) + t];
    __syncthreads();
    const int lkk = t & 15, lr = t >> 4;
    const int tx = t & 15, ty = t >> 4;
    float acc[4][2] = {};
    for (int k0 = 0; k0 < DD_; k0 += 16) {
        #pragma unroll
        for (int rr = 0; rr < 64; rr += 16)
            As[lkk][lr + rr] = x[(size_t)sidx[lr + rr] * DD_ + k0 + lkk];
        #pragma unroll
        for (int jj = 0; jj < 32; jj += 16)
            Bs[lkk][lr + jj] = W1[(size_t)(bx * 32 + lr + jj) * DD_ + k0 + lkk];
        __syncthreads();
        #pragma unroll
        for (int kk = 0; kk < 16; ++kk) {
            float a[4], b[2];
            #pragma unroll
            for (int u = 0; u < 4; ++u) a[u] = As[kk][ty * 4 + u];
            #pragma unroll
            for (int v = 0; v < 2; ++v) b[v] = Bs[kk][tx * 2 + v];
            #pragma unroll
            for (int u = 0; u < 4; ++u)
                #pragma unroll
                for (int v = 0; v < 2; ++v)
                    acc[u][v] += a[u] * b[v];
        }
        __syncthreads();
    }
    const int j0 = bx * 32 + tx * 2;
    const float b1v0 = b1[j0], b1v1 = b1[j0 + 1];
    #pragma unroll
    for (int u = 0; u < 4; ++u) {
        int r = rbase + ty * 4 + u;
        float2 hv;
        hv.x = tanhf(acc[u][0] + b1v0);
        hv.y = tanhf(acc[u][1] + b1v1);
        *reinterpret_cast<float2*>(&h[(size_t)r * HH_ + j0]) = hv;
    }
}

// ---------------- K3: M rows (3 terms x 2048 pairs) x H, and X rows x D ----------------
__global__ void k_Mx(const float* __restrict__ h, const float* __restrict__ c,
                     const float* __restrict__ x,
                     const int* __restrict__ i0, const int* __restrict__ i1,
                     const int* __restrict__ i2, const int* __restrict__ i3,
                     float* __restrict__ M, float* __restrict__ X) {
    const int bb = blockIdx.x;
    const int t = threadIdx.x;
    if (bb < 4096) {
        int gid = bb * 256 + t;   // 0..2048*512-1
        int i = gid & (HH_ - 1);
        int sp = gid >> 9;
        int s = sp >> 10;         // 0=pos, 1=neg
        int p = sp & 1023;
        float ha = h[((size_t)(s * 2) * 1024 + p) * HH_ + i];
        float hb = h[((size_t)(s * 2 + 1) * 1024 + p) * HH_ + i];
        float ci = c[i];
        float da = 1.f - ha * ha, db = 1.f - hb * hb;
        float sign = s ? -1.f : 1.f;
        const size_t TERM = (size_t)2048 * HH_;
        M[0 * TERM + gid] = sign * (da * da * ci);
        M[1 * TERM + gid] = sign * (-2.f * da * db * ci);
        M[2 * TERM + gid] = sign * (db * db * ci);
    } else {
        int gid = (bb - 4096) * 256 + t;  // 0..2048*256-1
        int j = gid & (DD_ - 1);
        int sp = gid >> 8;
        int s = sp >> 10, p = sp & 1023;
        int ia = s ? i2[p] : i0[p];
        int ib = s ? i3[p] : i1[p];
        float xa = x[(size_t)ia * DD_ + j];
        float xb = x[(size_t)ib * DD_ + j];
        const size_t TERM = (size_t)2048 * DD_;
        X[0 * TERM + gid] = xa * xa;
        X[1 * TERM + gid] = xa * xb;
        X[2 * TERM + gid] = xb * xb;
    }
}

// ---------------- K4: partial col-sums of M (b1) and hd (W2) ----------------
// MUST run before k_gemm2 (gemm2 partials alias h). grid 96.
__global__ void k_tail1(const float* __restrict__ M, const float* __restrict__ h,
                        float* __restrict__ pb1, float* __restrict__ phd) {
    const int bb = blockIdx.x;
    const int t = threadIdx.x;
    if (bb < 64) {
        int kb = bb >> 1;                 // 0..31, chunks of 192 rows
        int i = (bb & 1) * 256 + t;
        float s = 0.f;
        for (int k = kb * 192; k < kb * 192 + 192; ++k)
            s += M[(size_t)k * HH_ + i];
        pb1[kb * HH_ + i] = s;
    } else {
        int b2 = bb - 64;                 // 0..31
        int kb = b2 >> 1;                 // 0..15, chunks of 64 pairs
        int i = (b2 & 1) * 256 + t;
        float s = 0.f;
        for (int p = kb * 64; p < kb * 64 + 64; ++p) {
            float d0 = h[(size_t)p * HH_ + i] - h[(size_t)(1024 + p) * HH_ + i];
            float d1 = h[(size_t)(2048 + p) * HH_ + i] - h[(size_t)(3072 + p) * HH_ + i];
            s += d0 * d0 - d1 * d1;
        }
        phd[kb * HH_ + i] = s;
    }
}

// ---------------- K5: part[kb][i][j] = sum_{k in chunk of 384} M[k][i]*X[k][j] ----------------
// grid (4, 8, 16) = 512 blocks; part aliases h (dead after k_tail1)
__global__ __launch_bounds__(256) void k_gemm2(
    const float* __restrict__ M, const float* __restrict__ X,
    float* __restrict__ part) {
    __shared__ float Ms[16][68];
    __shared__ float Xs[16][68];
    const int t = threadIdx.x;
    const int bx = blockIdx.x;   // j block 0..3
    const int by = blockIdx.y;   // i block 0..7
    const int kb = blockIdx.z;   // 0..15 split-K
    const int li = t & 63, lk = t >> 6;
    const int tx = t & 15, ty = t >> 4;
    float acc[4][4] = {};
    const int kend = kb * 384 + 384;
    for (int k0 = kb * 384; k0 < kend; k0 += 16) {
        #pragma unroll
        for (int kk4 = 0; kk4 < 16; kk4 += 4) {
            Ms[lk + kk4][li] = M[(size_t)(k0 + lk + kk4) * HH_ + by * 64 + li];
            Xs[lk + kk4][li] = X[(size_t)(k0 + lk + kk4) * DD_ + bx * 64 + li];
        }
        __syncthreads();
        #pragma unroll
        for (int kk = 0; kk < 16; ++kk) {
            float a[4], b[4];
            #pragma unroll
            for (int u = 0; u < 4; ++u) a[u] = Ms[kk][ty * 4 + u];
            #pragma unroll
            for (int v = 0; v < 4; ++v) b[v] = Xs[kk][tx * 4 + v];
            #pragma unroll
            for (int u = 0; u < 4; ++u)
                #pragma unroll
                for (int v = 0; v < 4; ++v)
                    acc[u][v] += a[u] * b[v];
        }
        __syncthreads();
    }
    const int j0 = bx * 64 + tx * 4;
    #pragma unroll
    for (int u = 0; u < 4; ++u) {
        int i = by * 64 + ty * 4 + u;
        float4 v4 = {acc[u][0], acc[u][1], acc[u][2], acc[u][3]};
        *reinterpret_cast<float4*>(&part[((size_t)kb * HH_ + i) * DD_ + j0]) = v4;
    }
}

// ---------------- K6: reduce split-K partials -> out[0 .. H*D) ----------------
__global__ void k_w1red(const float* __restrict__ part, float* __restrict__ out) {
    int gid = blockIdx.x * 256 + threadIdx.x;  // 0..131071
    float s = 0.f;
    #pragma unroll
    for (int kb = 0; kb < 16; ++kb) s += part[(size_t)kb * (HH_ * DD_) + gid];
    out[gid] = s;
}

// ---------------- K7: finalize b1d, W2d broadcast, b2d zeros ----------------
__global__ void k_tail2(const float* __restrict__ pb1, const float* __restrict__ phd,
                        float* __restrict__ out) {
    int gid = blockIdx.x * 256 + threadIdx.x;  // 0..33343
    const int HD = HH_ * DD_;
    if (gid < HH_) {
        float s = 0.f;
        #pragma unroll
        for (int kb = 0; kb < 32; ++kb) s += pb1[kb * HH_ + gid];
        out[HD + gid] = s;
    } else if (gid < HH_ + OO_ * HH_) {
        int i = (gid - HH_) & (HH_ - 1);
        float s = 0.f;
        #pragma unroll
        for (int kb = 0; kb < 16; ++kb) s += phd[kb * HH_ + i];
        out[HD + gid] = s;
    } else if (gid < HH_ + OO_ * HH_ + OO_) {
        out[HD + gid] = 0.f;
    }
}

extern "C" void kernel_launch(void* const* d_in, const int* in_sizes, int n_in,
                              void* d_out, int out_size, void* d_ws, size_t ws_size,
                              hipStream_t stream) {
    const float* x  = (const float*)d_in[0];
    const float* W1 = (const float*)d_in[1];
    const float* b1 = (const float*)d_in[2];
    const float* W2 = (const float*)d_in[3];
    // d_in[4] = b2 (unused: b2 Jacobians cancel)
    const int* ap = (const int*)d_in[5];
    const int* p  = (const int*)d_in[6];
    const int* an = (const int*)d_in[7];
    const int* nI = (const int*)d_in[8];
    float* out = (float*)d_out;
    float* ws = (float*)d_ws;

    // workspace layout (floats), total ~6.84M floats = 27.4 MB
    float* h    = ws;                   // 4096*512 = 2097152; REUSED as gemm2 partials
    float* M    = h + 2097152;          // 6144*512 = 3145728
    float* X    = M + 3145728;          // 6144*256 = 1572864
    float* c    = X + 1572864;          // 512
    float* pb1  = c + 512;              // 32*512 = 16384
    float* phd  = pb1 + 16384;          // 16*512 = 8192
    float* part = h;                    // 16*131072 = 2097152 (exactly h's size)

    k_c<<<dim3(2), dim3(256), 0, stream>>>(W2, c);
    k_gemm1<<<dim3(16, 64), dim3(256), 0, stream>>>(x, W1, b1, ap, p, an, nI, h);
    k_Mx<<<dim3(6144), dim3(256), 0, stream>>>(h, c, x, ap, p, an, nI, M, X);
    k_tail1<<<dim3(96), dim3(256), 0, stream>>>(M, h, pb1, phd);
    k_gemm2<<<dim3(4, 8, 16), dim3(256), 0, stream>>>(M, X, part);
    k_w1red<<<dim3(512), dim3(256), 0, stream>>>(part, out);
    k_tail2<<<dim3(131), dim3(256), 0, stream>>>(pb1, phd, out);
}

// Round 3
// 36.359 us; speedup vs baseline: 3.8698x; 2.7138x over previous
//
#include <hip/hip_runtime.h>
#include <math.h>

#define DD_ 256
#define HH_ 512
#define OO_ 64

typedef __attribute__((ext_vector_type(8))) short bf16x8s;
typedef __attribute__((ext_vector_type(4))) float f32x4;

__device__ __forceinline__ unsigned short f2bf(float f) {
    unsigned u = __float_as_uint(f);
    u += 0x7FFF + ((u >> 16) & 1);   // round-to-nearest-even
    return (unsigned short)(u >> 16);
}
__device__ __forceinline__ float bf2f(unsigned short h) {
    return __uint_as_float(((unsigned)h) << 16);
}
// XOR swizzle of the 16B slot within a 64B LDS row: 2-way-max bank aliasing
__device__ __forceinline__ int swz4(int r, int g) {
    return g ^ (r & 3) ^ ((r >> 2) & 3);
}

// ============ K1: h = tanh(x[gather] . W1^T + b1), split-bf16 MFMA ============
// grid (8 nblk, 64 mblk); block 64m x 64n, 4 waves of 32x32; K=256
__global__ __launch_bounds__(256) void k_gemm1(
    const float* __restrict__ x, const float* __restrict__ W1, const float* __restrict__ b1,
    const int* __restrict__ i0p, const int* __restrict__ i1p,
    const int* __restrict__ i2p, const int* __restrict__ i3p,
    float* __restrict__ h) {
    __shared__ short Ah[64 * 32], Al[64 * 32], Bh[64 * 32], Bl[64 * 32];
    __shared__ int sidx[64];
    const int t = threadIdx.x;
    const int n0 = blockIdx.x * 64;
    const int rbase = blockIdx.y * 64;
    const int set = rbase >> 10;
    const int* I = (set == 0) ? i0p : (set == 1) ? i1p : (set == 2) ? i2p : i3p;
    if (t < 64) sidx[t] = I[(rbase & 1023) + t];
    __syncthreads();
    const int row = t >> 2, q = t & 3;          // staging: row 0..63, 16B slot 0..3
    const int l = t & 63, w = t >> 6;
    const int wm = w >> 1, wn = w & 1;          // wave 2x2 over 64x64 tile
    const int lm = l & 15, g = l >> 4;          // frag: m/n = lm, k-slot = g
    const int sw = swz4(row, q);
    f32x4 acc[2][2] = {};
    for (int k0 = 0; k0 < DD_; k0 += 32) {
        {   // stage A: gathered x rows, fp32 -> bf16 hi/lo
            const float* src = x + (size_t)sidx[row] * DD_ + k0 + q * 8;
            float4 v0 = *(const float4*)src;
            float4 v1 = *(const float4*)(src + 4);
            float f[8] = {v0.x, v0.y, v0.z, v0.w, v1.x, v1.y, v1.z, v1.w};
            bf16x8s hi, lo;
            #pragma unroll
            for (int j = 0; j < 8; ++j) {
                unsigned short hh = f2bf(f[j]);
                hi[j] = (short)hh;
                lo[j] = (short)f2bf(f[j] - bf2f(hh));
            }
            *(bf16x8s*)(&Ah[(row * 4 + sw) * 8]) = hi;
            *(bf16x8s*)(&Al[(row * 4 + sw) * 8]) = lo;
        }
        {   // stage B: W1 rows (already n-major, k-contig)
            const float* src = W1 + (size_t)(n0 + row) * DD_ + k0 + q * 8;
            float4 v0 = *(const float4*)src;
            float4 v1 = *(const float4*)(src + 4);
            float f[8] = {v0.x, v0.y, v0.z, v0.w, v1.x, v1.y, v1.z, v1.w};
            bf16x8s hi, lo;
            #pragma unroll
            for (int j = 0; j < 8; ++j) {
                unsigned short hh = f2bf(f[j]);
                hi[j] = (short)hh;
                lo[j] = (short)f2bf(f[j] - bf2f(hh));
            }
            *(bf16x8s*)(&Bh[(row * 4 + sw) * 8]) = hi;
            *(bf16x8s*)(&Bl[(row * 4 + sw) * 8]) = lo;
        }
        __syncthreads();
        bf16x8s ah[2], al[2], bh[2], bl[2];
        #pragma unroll
        for (int mi = 0; mi < 2; ++mi) {
            int r = wm * 32 + mi * 16 + lm;
            ah[mi] = *(const bf16x8s*)(&Ah[(r * 4 + swz4(r, g)) * 8]);
            al[mi] = *(const bf16x8s*)(&Al[(r * 4 + swz4(r, g)) * 8]);
        }
        #pragma unroll
        for (int nj = 0; nj < 2; ++nj) {
            int r = wn * 32 + nj * 16 + lm;
            bh[nj] = *(const bf16x8s*)(&Bh[(r * 4 + swz4(r, g)) * 8]);
            bl[nj] = *(const bf16x8s*)(&Bl[(r * 4 + swz4(r, g)) * 8]);
        }
        #pragma unroll
        for (int mi = 0; mi < 2; ++mi)
            #pragma unroll
            for (int nj = 0; nj < 2; ++nj) {
                acc[mi][nj] = __builtin_amdgcn_mfma_f32_16x16x32_bf16(ah[mi], bh[nj], acc[mi][nj], 0, 0, 0);
                acc[mi][nj] = __builtin_amdgcn_mfma_f32_16x16x32_bf16(ah[mi], bl[nj], acc[mi][nj], 0, 0, 0);
                acc[mi][nj] = __builtin_amdgcn_mfma_f32_16x16x32_bf16(al[mi], bh[nj], acc[mi][nj], 0, 0, 0);
            }
        __syncthreads();
    }
    #pragma unroll
    for (int mi = 0; mi < 2; ++mi)
        #pragma unroll
        for (int nj = 0; nj < 2; ++nj) {
            int j = n0 + wn * 32 + nj * 16 + lm;
            float bv = b1[j];
            #pragma unroll
            for (int qq = 0; qq < 4; ++qq) {
                int r = rbase + wm * 32 + mi * 16 + g * 4 + qq;   // D row = (l>>4)*4+reg
                h[(size_t)r * HH_ + j] = tanhf(acc[mi][nj][qq] + bv);
            }
        }
}

// ============ K2: build Mt[512][6144] bf16, Xt[256][6144] bf16, b1/hd partials ====
// bb<256: Mt blocks (8 iblk x 32 pblk); bb>=256: Xt blocks (4 jblk x 32 pblk)
__global__ __launch_bounds__(256) void k_build(
    const float* __restrict__ h, const float* __restrict__ x,
    const float* __restrict__ W2,
    const int* __restrict__ ap, const int* __restrict__ pI,
    const int* __restrict__ an, const int* __restrict__ nI,
    short* __restrict__ Mt, short* __restrict__ Xt,
    float* __restrict__ pb1, float* __restrict__ phd) {
    const int t = threadIdx.x;
    const int bb = blockIdx.x;
    if (bb < 256) {
        const int iblk = bb >> 5, pblk = bb & 31;
        const int i = iblk * 64 + (t >> 2), pq = t & 3;
        const int p0 = pblk * 64;
        const int s = p0 >> 10;
        const float sgn = s ? -1.f : 1.f;
        float ci = 0.f;
        #pragma unroll
        for (int o = 0; o < OO_; ++o) { float wv = W2[o * HH_ + i]; ci += wv * wv; }
        const int pb = (p0 & 1023) + pq * 16;
        const float* hA = h + (size_t)(s * 2048 + pb) * HH_ + i;
        const float* hB = hA + (size_t)1024 * HH_;
        short m[3][16];
        float b1p = 0.f, hdp = 0.f;
        #pragma unroll
        for (int pp = 0; pp < 16; ++pp) {
            float ha = hA[(size_t)pp * HH_];
            float hb = hB[(size_t)pp * HH_];
            float da = 1.f - ha * ha, db = 1.f - hb * hb;
            float s11 = sgn * (da * da * ci);
            float s12 = sgn * (-2.f * da * db * ci);
            float s22 = sgn * (db * db * ci);
            m[0][pp] = (short)f2bf(s11);
            m[1][pp] = (short)f2bf(s12);
            m[2][pp] = (short)f2bf(s22);
            b1p += s11 + s12 + s22;
            float d = ha - hb;
            hdp += sgn * d * d;
        }
        size_t base = (size_t)i * 6144 + p0 + pq * 16;
        #pragma unroll
        for (int term = 0; term < 3; ++term) {
            bf16x8s v0, v1;
            #pragma unroll
            for (int j2 = 0; j2 < 8; ++j2) { v0[j2] = m[term][j2]; v1[j2] = m[term][j2 + 8]; }
            *(bf16x8s*)(&Mt[base + (size_t)term * 2048]) = v0;
            *(bf16x8s*)(&Mt[base + (size_t)term * 2048 + 8]) = v1;
        }
        b1p += __shfl_xor(b1p, 1); b1p += __shfl_xor(b1p, 2);
        hdp += __shfl_xor(hdp, 1); hdp += __shfl_xor(hdp, 2);
        if (pq == 0) { pb1[pblk * HH_ + i] = b1p; phd[pblk * HH_ + i] = hdp; }
    } else {
        __shared__ int sia[64], sib[64];
        const int b2 = bb - 256;
        const int jblk = b2 >> 5, pblk = b2 & 31;
        const int j = jblk * 64 + (t >> 2), pq = t & 3;
        const int p0 = pblk * 64;
        const int s = p0 >> 10;
        const int* IA = s ? an : ap;
        const int* IB = s ? nI : pI;
        if (t < 64) sia[t] = IA[(p0 & 1023) + t];
        else if (t < 128) sib[t - 64] = IB[(p0 & 1023) + (t - 64)];
        __syncthreads();
        short xv[3][16];
        #pragma unroll
        for (int pp = 0; pp < 16; ++pp) {
            int pl = pq * 16 + pp;
            float xa = x[(size_t)sia[pl] * DD_ + j];
            float xb = x[(size_t)sib[pl] * DD_ + j];
            xv[0][pp] = (short)f2bf(xa * xa);
            xv[1][pp] = (short)f2bf(xa * xb);
            xv[2][pp] = (short)f2bf(xb * xb);
        }
        size_t base = (size_t)j * 6144 + p0 + pq * 16;
        #pragma unroll
        for (int term = 0; term < 3; ++term) {
            bf16x8s v0, v1;
            #pragma unroll
            for (int j2 = 0; j2 < 8; ++j2) { v0[j2] = xv[term][j2]; v1[j2] = xv[term][j2 + 8]; }
            *(bf16x8s*)(&Xt[base + (size_t)term * 2048]) = v0;
            *(bf16x8s*)(&Xt[base + (size_t)term * 2048 + 8]) = v1;
        }
    }
}

// ============ K3: part[kb][i][j] = sum_{k chunk 384} Mt[i][k]*Xt[j][k], bf16 MFMA ====
// grid (4 jblk, 8 iblk, 16 kb); block 64i x 64j, 4 waves of 32x32
__global__ __launch_bounds__(256) void k_gemm2(
    const short* __restrict__ Mt, const short* __restrict__ Xt,
    float* __restrict__ part) {
    __shared__ short As[64 * 32], Bs[64 * 32];
    const int t = threadIdx.x;
    const int j0 = blockIdx.x * 64;
    const int i0 = blockIdx.y * 64;
    const int kb = blockIdx.z;
    const int row = t >> 2, q = t & 3;
    const int l = t & 63, w = t >> 6;
    const int wm = w >> 1, wn = w & 1;
    const int lm = l & 15, g = l >> 4;
    const int sw = swz4(row, q);
    f32x4 acc[2][2] = {};
    for (int ks = 0; ks < 12; ++ks) {
        const int k0 = kb * 384 + ks * 32;
        *(bf16x8s*)(&As[(row * 4 + sw) * 8]) =
            *(const bf16x8s*)(&Mt[(size_t)(i0 + row) * 6144 + k0 + q * 8]);
        *(bf16x8s*)(&Bs[(row * 4 + sw) * 8]) =
            *(const bf16x8s*)(&Xt[(size_t)(j0 + row) * 6144 + k0 + q * 8]);
        __syncthreads();
        bf16x8s a[2], b[2];
        #pragma unroll
        for (int mi = 0; mi < 2; ++mi) {
            int r = wm * 32 + mi * 16 + lm;
            a[mi] = *(const bf16x8s*)(&As[(r * 4 + swz4(r, g)) * 8]);
        }
        #pragma unroll
        for (int nj = 0; nj < 2; ++nj) {
            int r = wn * 32 + nj * 16 + lm;
            b[nj] = *(const bf16x8s*)(&Bs[(r * 4 + swz4(r, g)) * 8]);
        }
        #pragma unroll
        for (int mi = 0; mi < 2; ++mi)
            #pragma unroll
            for (int nj = 0; nj < 2; ++nj)
                acc[mi][nj] = __builtin_amdgcn_mfma_f32_16x16x32_bf16(a[mi], b[nj], acc[mi][nj], 0, 0, 0);
        __syncthreads();
    }
    #pragma unroll
    for (int mi = 0; mi < 2; ++mi)
        #pragma unroll
        for (int nj = 0; nj < 2; ++nj) {
            int j = j0 + wn * 32 + nj * 16 + lm;
            #pragma unroll
            for (int qq = 0; qq < 4; ++qq) {
                int i = i0 + wm * 32 + mi * 16 + g * 4 + qq;
                part[((size_t)kb * HH_ + i) * DD_ + j] = acc[mi][nj][qq];
            }
        }
}

// ============ K4: reductions + broadcast + zeros ============
__global__ void k_tail(const float* __restrict__ part, const float* __restrict__ pb1,
                       const float* __restrict__ phd, float* __restrict__ out) {
    int gid = blockIdx.x * 256 + threadIdx.x;
    const int HD = HH_ * DD_;   // 131072
    if (gid < HD) {
        float sv = 0.f;
        #pragma unroll
        for (int kb = 0; kb < 16; ++kb) sv += part[(size_t)kb * HD + gid];
        out[gid] = sv;
    } else if (gid < HD + HH_) {
        int i = gid - HD;
        float sv = 0.f;
        #pragma unroll
        for (int kb = 0; kb < 32; ++kb) sv += pb1[kb * HH_ + i];
        out[gid] = sv;
    } else if (gid < HD + HH_ + OO_ * HH_) {
        int i = (gid - HD - HH_) & (HH_ - 1);
        float sv = 0.f;
        #pragma unroll
        for (int kb = 0; kb < 32; ++kb) sv += phd[kb * HH_ + i];
        out[gid] = sv;
    } else if (gid < HD + HH_ + OO_ * HH_ + OO_) {
        out[gid] = 0.f;
    }
}

extern "C" void kernel_launch(void* const* d_in, const int* in_sizes, int n_in,
                              void* d_out, int out_size, void* d_ws, size_t ws_size,
                              hipStream_t stream) {
    const float* x  = (const float*)d_in[0];
    const float* W1 = (const float*)d_in[1];
    const float* b1 = (const float*)d_in[2];
    const float* W2 = (const float*)d_in[3];
    // d_in[4] = b2 (unused: b2 Jacobians cancel)
    const int* ap = (const int*)d_in[5];
    const int* pI = (const int*)d_in[6];
    const int* an = (const int*)d_in[7];
    const int* nI = (const int*)d_in[8];
    float* out = (float*)d_out;
    float* ws = (float*)d_ws;

    // workspace (float units): total 6586368 floats = 26.3 MB
    float* h    = ws;                         // 4096*512  = 2097152
    float* part = ws + 2097152;               // 16*131072 = 2097152
    short* Mt   = (short*)(ws + 4194304);     // 512*6144 shorts = 1572864 floats
    short* Xt   = (short*)(ws + 5767168);     // 256*6144 shorts =  786432 floats
    float* pb1  = ws + 6553600;               // 32*512
    float* phd  = ws + 6569984;               // 32*512

    k_gemm1<<<dim3(8, 64), dim3(256), 0, stream>>>(x, W1, b1, ap, pI, an, nI, h);
    k_build<<<dim3(384), dim3(256), 0, stream>>>(h, x, W2, ap, pI, an, nI, Mt, Xt, pb1, phd);
    k_gemm2<<<dim3(4, 8, 16), dim3(256), 0, stream>>>(Mt, Xt, part);
    k_tail<<<dim3(643), dim3(256), 0, stream>>>(part, pb1, phd, out);
}